// Round 1
// baseline (587.129 us; speedup 1.0000x reference)
//
#include <hip/hip_runtime.h>

// SeparableConv3D: x[8,3,32,256,256] fp32, depthwise K=5 cross-correlation
// along W, then H, then T, zero 'same' padding. Fused single-pass kernel:
// per-block LDS tile (8,8,32) output with +-2 halo in all three dims.

#define N_  8
#define C_  3
#define T_  32
#define H_  256
#define W_  256
#define K_  5
#define PAD 2

#define TT 8
#define TH 8
#define TW 32

#define AT (TT + 4)   // 12
#define AH (TH + 4)   // 12
#define AW (TW + 4)   // 36

__global__ __launch_bounds__(256)
void sep3d_fused(const float* __restrict__ x,
                 const float* __restrict__ w1,
                 const float* __restrict__ w2,
                 const float* __restrict__ w3,
                 float* __restrict__ out)
{
    __shared__ float sA[AT * AH * AW];   // 5184 floats: input halo tile / later bufC
    __shared__ float sB[AT * AH * TW];   // 4608 floats: after W-conv

    const int tid = threadIdx.x;

    // Block decode: grid = ((H/TH)*(W/TW), T/TT, N*C)
    const int bx   = blockIdx.x;
    const int wblk = bx % (W_ / TW);
    const int hblk = bx / (W_ / TW);
    const int tblk = blockIdx.y;
    const int nc   = blockIdx.z;
    const int c    = nc % C_;

    const int t0 = tblk * TT;
    const int h0 = hblk * TH;
    const int w0 = wblk * TW;

    const float* xb = x   + (size_t)nc * (T_ * H_ * W_);
    float*       ob = out + (size_t)nc * (T_ * H_ * W_);

    // Per-channel taps (broadcast loads, served by cache)
    float k1[K_], k2[K_], k3[K_];
#pragma unroll
    for (int k = 0; k < K_; ++k) {
        k1[k] = w1[c * K_ + k];
        k2[k] = w2[c * K_ + k];
        k3[k] = w3[c * K_ + k];
    }

    // Stage 1: global -> LDS halo tile (zero-fill out of range)
    for (int i = tid; i < AT * AH * AW; i += 256) {
        int lw = i % AW;
        int lh = (i / AW) % AH;
        int lt = i / (AW * AH);
        int t = t0 + lt - PAD;
        int h = h0 + lh - PAD;
        int w = w0 + lw - PAD;
        float v = 0.0f;
        if ((unsigned)t < T_ && (unsigned)h < H_ && (unsigned)w < W_)
            v = xb[((size_t)t * H_ + h) * W_ + w];
        sA[i] = v;
    }
    __syncthreads();

    // Stage 2: conv along W  (sA[12][12][36] -> sB[12][12][32])
    for (int i = tid; i < AT * AH * TW; i += 256) {
        int lw = i % TW;
        int lh = (i / TW) % AH;
        int lt = i / (TW * AH);
        const float* p = &sA[(lt * AH + lh) * AW + lw];
        float acc = 0.0f;
#pragma unroll
        for (int k = 0; k < K_; ++k) acc += p[k] * k1[k];
        sB[i] = acc;
    }
    __syncthreads();

    // Stage 3: conv along H  (sB[12][12][32] -> sC[12][8][32], aliased over sA)
    float* sC = sA;
    for (int i = tid; i < AT * TH * TW; i += 256) {
        int lw = i % TW;
        int lh = (i / TW) % TH;
        int lt = i / (TW * TH);
        const float* p = &sB[(lt * AH + lh) * TW + lw];
        float acc = 0.0f;
#pragma unroll
        for (int k = 0; k < K_; ++k) acc += p[k * TW] * k2[k];
        sC[i] = acc;
    }
    __syncthreads();

    // Stage 4: conv along T + coalesced global store
    for (int i = tid; i < TT * TH * TW; i += 256) {
        int lw = i % TW;
        int lh = (i / TW) % TH;
        int lt = i / (TW * TH);
        const float* p = &sC[(lt * TH + lh) * TW + lw];
        float acc = 0.0f;
#pragma unroll
        for (int k = 0; k < K_; ++k) acc += p[k * TH * TW] * k3[k];
        ob[((size_t)(t0 + lt) * H_ + (h0 + lh)) * W_ + (w0 + lw)] = acc;
    }
}

extern "C" void kernel_launch(void* const* d_in, const int* in_sizes, int n_in,
                              void* d_out, int out_size, void* d_ws, size_t ws_size,
                              hipStream_t stream)
{
    const float* x  = (const float*)d_in[0];
    const float* w1 = (const float*)d_in[1];
    const float* w2 = (const float*)d_in[2];
    const float* w3 = (const float*)d_in[3];
    float* out = (float*)d_out;

    dim3 grid((H_ / TH) * (W_ / TW), T_ / TT, N_ * C_);
    sep3d_fused<<<grid, 256, 0, stream>>>(x, w1, w2, w3, out);
}

// Round 2
// 433.885 us; speedup vs baseline: 1.3532x; 1.3532x over previous
//
#include <hip/hip_runtime.h>

// SeparableConv3D fused single-pass: x[8,3,32,256,256] fp32, depthwise K=5
// cross-correlation along W, H, T, zero 'same' padding.
//
// Structure: block = (TH=16 x TW=64) spatial tile of one (n,c); loop over t.
// Per t-slice: x halo (20x68) -> LDS (precomputed offsets), W-conv via
// ds_read_b128 -> LDS y (20x64), H-conv via 5x ds_read_b128 -> z in regs,
// T-conv as a 4-deep float4 register ring; out(t-2) stored each iter.
// HBM traffic: 201*1.33 read + 201 write ~ 470 MB -> ~75 us floor.

#define N_  8
#define C_  3
#define T_  32
#define H_  256
#define W_  256
#define K_  5
#define HW_ (H_ * W_)

#define TH 16
#define TW 64
// sx logical: 20 rows x 68 cols = 1360 floats; padded to 1536 so that the
// strided staging loop (6 x 256 = 1536 slots) can write zeros harmlessly.
#define SX_PAD_FLOATS 1536

__global__ __launch_bounds__(256)
void sep3d_fused2(const float* __restrict__ x,
                  const float* __restrict__ w1,
                  const float* __restrict__ w2,
                  const float* __restrict__ w3,
                  float* __restrict__ out)
{
    __shared__ float4 sx4[SX_PAD_FLOATS / 4];   // 20x68 used (17 float4 per row)
    __shared__ float4 sy4[20 * (TW / 4)];       // 20x64 floats = 20x16 float4
    float* sx = (float*)sx4;

    const int tid = threadIdx.x;
    const int nc  = blockIdx.z;          // n*C + c
    const int c   = nc % C_;
    const int h0  = blockIdx.y * TH;
    const int w0  = blockIdx.x * TW;

    const float* xnc = x   + (size_t)nc * (T_ * HW_);
    float*       onc = out + (size_t)nc * (T_ * HW_);

    float k1[K_], k2[K_], k3[K_];
#pragma unroll
    for (int k = 0; k < K_; ++k) {
        k1[k] = w1[c * K_ + k];
        k2[k] = w2[c * K_ + k];
        k3[k] = w3[c * K_ + k];
    }

    // ---- Precompute stage-1 halo-load descriptors (t-invariant) ----
    int  s1_off[6];
    bool s1_ok[6];
#pragma unroll
    for (int j = 0; j < 6; ++j) {
        int i   = tid + j * 256;         // [0, 1536)
        int row = i / 68;
        int col = i - row * 68;
        int gh  = h0 + row - 2;
        int gw  = w0 + col - 2;
        s1_ok[j]  = (i < 1360) && ((unsigned)gh < H_) && ((unsigned)gw < W_);
        s1_off[j] = gh * W_ + gw;
    }

    // ---- Stage-3 (H-conv + store) constants ----
    const int row3 = tid >> 4;           // 0..15
    const int seg3 = tid & 15;           // 0..15
    float* gst = onc + (h0 + row3) * W_ + (w0 + 4 * seg3);

    // T-conv register ring: at start of iter t,
    // a0=partial out(t-2), a1=out(t-1), a2=out(t), a3=out(t+1). Init 0.
    float4 a0 = {0,0,0,0}, a1 = a0, a2 = a0, a3 = a0;

    for (int t = 0; t < T_; ++t) {
        const float* xt = xnc + (size_t)t * HW_;

        // Stage 1: x slice halo -> LDS
#pragma unroll
        for (int j = 0; j < 6; ++j) {
            float v = 0.0f;
            if (s1_ok[j]) v = xt[s1_off[j]];
            sx[tid + j * 256] = v;
        }
        __syncthreads();

        // Stage 2: W-conv, 4 outputs per task, 320 tasks (20 rows x 16 segs)
#pragma unroll
        for (int rep = 0; rep < 2; ++rep) {
            int task = tid + rep * 256;
            if (task < 320) {
                int seg = task & 15, row = task >> 4;
                const float4* p = (const float4*)&sx[row * 68 + 4 * seg];
                float4 aa = p[0], bb = p[1];
                float xv0 = aa.x, xv1 = aa.y, xv2 = aa.z, xv3 = aa.w;
                float xv4 = bb.x, xv5 = bb.y, xv6 = bb.z, xv7 = bb.w;
                float4 y;
                y.x = xv0*k1[0] + xv1*k1[1] + xv2*k1[2] + xv3*k1[3] + xv4*k1[4];
                y.y = xv1*k1[0] + xv2*k1[1] + xv3*k1[2] + xv4*k1[3] + xv5*k1[4];
                y.z = xv2*k1[0] + xv3*k1[1] + xv4*k1[2] + xv5*k1[3] + xv6*k1[4];
                y.w = xv3*k1[0] + xv4*k1[1] + xv5*k1[2] + xv6*k1[3] + xv7*k1[4];
                sy4[row * 16 + seg] = y;
            }
        }
        __syncthreads();

        // Stage 3: H-conv -> z (registers)
        float4 z = {0,0,0,0};
#pragma unroll
        for (int k = 0; k < K_; ++k) {
            float4 r = sy4[(row3 + k) * 16 + seg3];
            z.x += r.x * k2[k];
            z.y += r.y * k2[k];
            z.z += r.z * k2[k];
            z.w += r.w * k2[k];
        }

        // Stage 4: T-conv register ring update
        float4 done;
        done.x = a0.x + z.x * k3[4];
        done.y = a0.y + z.y * k3[4];
        done.z = a0.z + z.z * k3[4];
        done.w = a0.w + z.w * k3[4];
        if (t >= 2) *(float4*)(gst + (size_t)(t - 2) * HW_) = done;
        a0.x = a1.x + z.x * k3[3];  a0.y = a1.y + z.y * k3[3];
        a0.z = a1.z + z.z * k3[3];  a0.w = a1.w + z.w * k3[3];
        a1.x = a2.x + z.x * k3[2];  a1.y = a2.y + z.y * k3[2];
        a1.z = a2.z + z.z * k3[2];  a1.w = a2.w + z.w * k3[2];
        a2.x = a3.x + z.x * k3[1];  a2.y = a3.y + z.y * k3[1];
        a2.z = a3.z + z.z * k3[1];  a2.w = a3.w + z.w * k3[1];
        a3.x = z.x * k3[0];  a3.y = z.y * k3[0];
        a3.z = z.z * k3[0];  a3.w = z.w * k3[0];
    }

    // Epilogue: out(30) = a0, out(31) = a1 (z(32), z(33) are zero padding)
    *(float4*)(gst + (size_t)30 * HW_) = a0;
    *(float4*)(gst + (size_t)31 * HW_) = a1;
}

extern "C" void kernel_launch(void* const* d_in, const int* in_sizes, int n_in,
                              void* d_out, int out_size, void* d_ws, size_t ws_size,
                              hipStream_t stream)
{
    const float* x  = (const float*)d_in[0];
    const float* w1 = (const float*)d_in[1];
    const float* w2 = (const float*)d_in[2];
    const float* w3 = (const float*)d_in[3];
    float* out = (float*)d_out;

    dim3 grid(W_ / TW, H_ / TH, N_ * C_);   // 4 x 16 x 24 = 1536 blocks
    sep3d_fused2<<<grid, 256, 0, stream>>>(x, w1, w2, w3, out);
}